// Round 2
// baseline (189.222 us; speedup 1.0000x reference)
//
#include <hip/hip_runtime.h>

// x: [128][256][256][3] fp32, C: [768][4][256][4] fp32 -> [3072][1024]
// out[b,kl,hw] = S_x[b,hw] * S_C[kl]   (einsum has no shared labels -> factorizes)
//   S_x[b,h,w] = sum_{p1,p2,ch} x[b, p1*8+h, p2*8+w, ch]
//   S_C[kl]    = column sum of C over 3072 rows
//
// ws layout (floats), no zeroing needed -- every element overwritten each call:
//   psx[128][8][64]   partial S_x per 32-row group
//   psC[96][1024]     partial S_C per 32-row group
//   sC[1024]          final S_C (finalized by kernel B's b==0 blocks)

#define PSX_ELEMS (128 * 8 * 64)
#define PSC_ELEMS (96 * 1024)

// ---------- Kernel A: C column partial sums ----------
__global__ __launch_bounds__(256) void reduce_C_part(const float* __restrict__ C,
                                                     float4* __restrict__ psC) {
    const int p = blockIdx.x;
    const int t = threadIdx.x;
    const float4* row = (const float4*)(C + (size_t)p * 32 * 1024) + t;
    float4 a = {0.f, 0.f, 0.f, 0.f};
#pragma unroll
    for (int r = 0; r < 32; ++r) {
        float4 v = row[(size_t)r * 256];
        a.x += v.x; a.y += v.y; a.z += v.z; a.w += v.w;
    }
    psC[p * 256 + t] = a;
}

// ---------- Kernel B: x pixel-position partial sums (float4 streaming) ----------
__global__ __launch_bounds__(384) void reduce_x_part(const float* __restrict__ x,
                                                     const float* __restrict__ psC,
                                                     float* __restrict__ psx,
                                                     float* __restrict__ sC) {
    const int b  = blockIdx.y;
    const int bx = blockIdx.x;
    const int t  = threadIdx.x;
    const float4* base4 = (const float4*)(x + ((size_t)b * 256 + bx * 32) * 768);

    float4 acc[4];
#pragma unroll
    for (int mm = 0; mm < 4; ++mm) acc[mm] = (float4){0.f, 0.f, 0.f, 0.f};

#pragma unroll
    for (int jj = 0; jj < 4; ++jj)
#pragma unroll
        for (int mm = 0; mm < 4; ++mm) {
            float4 v = base4[(size_t)(mm + 4 * jj) * 384 + t];
            acc[mm].x += v.x; acc[mm].y += v.y; acc[mm].z += v.z; acc[mm].w += v.w;
        }

    __shared__ float4 lds4[8][193];   // padded to break bank alignment
    const int r  = t / 192;
    const int c4 = t % 192;
#pragma unroll
    for (int mm = 0; mm < 4; ++mm) lds4[2 * mm + r][c4] = acc[mm];
    __syncthreads();

    if (t < 64) {
        const int h = t >> 3, w = t & 7;
        const float* L = (const float*)&lds4[h][0];
        float s = 0.f;
#pragma unroll
        for (int g = 0; g < 32; ++g)
            s += L[3 * w + 24 * g] + L[3 * w + 1 + 24 * g] + L[3 * w + 2 + 24 * g];
        psx[(size_t)b * 512 + bx * 64 + t] = s;
    }

    if (b == 0 && t < 128) {          // finalize sC in the 8 (bx, b==0) blocks
        const int col = bx * 128 + t;
        float s = 0.f;
#pragma unroll
        for (int p = 0; p < 96; ++p) s += psC[p * 1024 + col];
        sC[col] = s;
    }
}

// ---------- Kernel C: outer-product expansion ----------
__global__ __launch_bounds__(256) void expand_kernel(const float* __restrict__ psx,
                                                     const float* __restrict__ sC,
                                                     float4* __restrict__ out) {
    const int b  = blockIdx.y;
    const int bx = blockIdx.x;
    const int t  = threadIdx.x;

    __shared__ float4 sxl4[16];
    __shared__ float  sCl[64];

    if (t < 64) {
        float s = 0.f;
#pragma unroll
        for (int g = 0; g < 8; ++g) s += psx[(size_t)b * 512 + g * 64 + t];
        ((float*)sxl4)[t] = s;
    } else if (t < 128) {
        sCl[t - 64] = sC[bx * 64 + (t - 64)];
    }
    __syncthreads();

    const float4 v = sxl4[t & 15];
    float4* ob = out + (size_t)b * 16384 + bx * 1024 + t;
#pragma unroll
    for (int u = 0; u < 4; ++u) {
        const float s = sCl[(t >> 4) + 16 * u];
        float4 rr; rr.x = v.x * s; rr.y = v.y * s; rr.z = v.z * s; rr.w = v.w * s;
        ob[256 * u] = rr;
    }
}

extern "C" void kernel_launch(void* const* d_in, const int* in_sizes, int n_in,
                              void* d_out, int out_size, void* d_ws, size_t ws_size,
                              hipStream_t stream) {
    const float* x = (const float*)d_in[0];
    const float* C = (const float*)d_in[1];
    float* out = (float*)d_out;

    float* psx = (float*)d_ws;
    float* psC = psx + PSX_ELEMS;
    float* sC  = psC + PSC_ELEMS;

    reduce_C_part<<<dim3(96), 256, 0, stream>>>(C, (float4*)psC);
    reduce_x_part<<<dim3(8, 128), 384, 0, stream>>>(x, psC, psx, sC);
    expand_kernel<<<dim3(16, 128), 256, 0, stream>>>(psx, sC, (float4*)out);
}